// Round 1
// baseline (184.897 us; speedup 1.0000x reference)
//
#include <hip/hip_runtime.h>

constexpr int H = 4096;
constexpr int W = 4096;
constexpr int NPIX = H * W;          // 16,777,216
constexpr int NV   = NPIX / 4;       // float4 count: 4,194,304
constexpr int W4   = W / 4;          // 1024 float4 per row

// ---- block-wide sum reduction (wave64 shfl + LDS across waves) ----
__device__ __forceinline__ float blockReduceSum(float val) {
    __shared__ float smem[8];
    const int lane = threadIdx.x & 63;
    const int wid  = threadIdx.x >> 6;
    #pragma unroll
    for (int off = 32; off > 0; off >>= 1) val += __shfl_down(val, off, 64);
    __syncthreads();                 // protect smem reuse across calls
    if (lane == 0) smem[wid] = val;
    __syncthreads();
    val = (threadIdx.x < (blockDim.x >> 6)) ? smem[threadIdx.x] : 0.f;
    if (wid == 0) {
        #pragma unroll
        for (int off = 32; off > 0; off >>= 1) val += __shfl_down(val, off, 64);
    }
    return val;                      // valid in thread 0
}

// ---- 3x3 cross-correlation (zero-padded) for 4 contiguous pixels ----
__device__ __forceinline__ void conv_row4(const float* __restrict__ p, int h, int w4,
                                          const float f[9], float cv[4]) {
    float a0 = 0.f, a1 = 0.f, a2 = 0.f, a3 = 0.f;
    #pragma unroll
    for (int dh = -1; dh <= 1; ++dh) {
        const int r = h + dh;
        float4 c = make_float4(0.f, 0.f, 0.f, 0.f);
        float left = 0.f, right = 0.f;
        if ((unsigned)r < (unsigned)H) {
            const float* row = p + (size_t)r * W;
            c = reinterpret_cast<const float4*>(row)[w4];
            const int w0 = w4 * 4;
            left  = (w0 > 0)      ? row[w0 - 1] : 0.f;
            right = (w0 + 4 < W)  ? row[w0 + 4] : 0.f;
        }
        const float* fr = f + (dh + 1) * 3;
        a0 += fr[0] * left + fr[1] * c.x + fr[2] * c.y;
        a1 += fr[0] * c.x  + fr[1] * c.y + fr[2] * c.z;
        a2 += fr[0] * c.y  + fr[1] * c.z + fr[2] * c.w;
        a3 += fr[0] * c.z  + fr[1] * c.w + fr[2] * right;
    }
    cv[0] = a0; cv[1] = a1; cv[2] = a2; cv[3] = a3;
}

// ---- K1: rr0 = sum(r0*r0), pAp = sum(p * conv(p)) ----
__global__ __launch_bounds__(256) void k1_reduce(const float* __restrict__ r0,
                                                 const float* __restrict__ p,
                                                 const float* __restrict__ filt,
                                                 float* __restrict__ sums) {
    float f[9];
    #pragma unroll
    for (int i = 0; i < 9; ++i) f[i] = filt[i];
    float rr0 = 0.f, pap = 0.f;
    const int stride = gridDim.x * blockDim.x;
    for (int v = blockIdx.x * blockDim.x + threadIdx.x; v < NV; v += stride) {
        const int h  = v >> 10;
        const int w4 = v & (W4 - 1);
        const float4 rv = reinterpret_cast<const float4*>(r0)[v];
        rr0 += rv.x * rv.x + rv.y * rv.y + rv.z * rv.z + rv.w * rv.w;
        const float4 pv = reinterpret_cast<const float4*>(p)[v];
        float cv[4];
        conv_row4(p, h, w4, f, cv);
        pap += pv.x * cv[0] + pv.y * cv[1] + pv.z * cv[2] + pv.w * cv[3];
    }
    rr0 = blockReduceSum(rr0);
    pap = blockReduceSum(pap);
    if (threadIdx.x == 0) {
        atomicAdd(&sums[0], rr0);
        atomicAdd(&sums[1], pap);
    }
}

// ---- K2: r1 = r0 - alpha*conv(p); phi_new = phi + alpha*p; r1_sum ----
__global__ __launch_bounds__(256) void k2_update(const float* __restrict__ r0,
                                                 const float* __restrict__ p,
                                                 const float* __restrict__ phi,
                                                 const float* __restrict__ filt,
                                                 float* __restrict__ sums,
                                                 float* __restrict__ out) {
    const float alpha = sums[0] / sums[1];
    float f[9];
    #pragma unroll
    for (int i = 0; i < 9; ++i) f[i] = filt[i];
    float4* __restrict__ r1_out  = reinterpret_cast<float4*>(out);
    float4* __restrict__ phi_out = reinterpret_cast<float4*>(out + 2 * (size_t)NPIX);
    float r1s = 0.f;
    const int stride = gridDim.x * blockDim.x;
    for (int v = blockIdx.x * blockDim.x + threadIdx.x; v < NV; v += stride) {
        const int h  = v >> 10;
        const int w4 = v & (W4 - 1);
        float cv[4];
        conv_row4(p, h, w4, f, cv);
        const float4 rv = reinterpret_cast<const float4*>(r0)[v];
        const float4 pv = reinterpret_cast<const float4*>(p)[v];
        const float4 ph = reinterpret_cast<const float4*>(phi)[v];
        float4 r1;
        r1.x = fmaf(-alpha, cv[0], rv.x);
        r1.y = fmaf(-alpha, cv[1], rv.y);
        r1.z = fmaf(-alpha, cv[2], rv.z);
        r1.w = fmaf(-alpha, cv[3], rv.w);
        r1_out[v] = r1;
        float4 pn;
        pn.x = fmaf(alpha, pv.x, ph.x);
        pn.y = fmaf(alpha, pv.y, ph.y);
        pn.z = fmaf(alpha, pv.z, ph.z);
        pn.w = fmaf(alpha, pv.w, ph.w);
        phi_out[v] = pn;
        r1s += r1.x * r1.x + r1.y * r1.y + r1.z * r1.z + r1.w * r1.w;
    }
    r1s = blockReduceSum(r1s);
    if (threadIdx.x == 0) atomicAdd(&sums[2], r1s);
}

// ---- K3: p_new = r1 + beta*p; write r1_sum scalar ----
__global__ __launch_bounds__(256) void k3_pnew(const float* __restrict__ p,
                                               const float* __restrict__ sums,
                                               float* __restrict__ out) {
    const float beta = sums[2] / sums[0];
    const float4* __restrict__ r1 = reinterpret_cast<const float4*>(out);
    float4* __restrict__ pn = reinterpret_cast<float4*>(out + (size_t)NPIX);
    const int stride = gridDim.x * blockDim.x;
    for (int v = blockIdx.x * blockDim.x + threadIdx.x; v < NV; v += stride) {
        const float4 r = r1[v];
        const float4 pv = reinterpret_cast<const float4*>(p)[v];
        float4 o;
        o.x = fmaf(beta, pv.x, r.x);
        o.y = fmaf(beta, pv.y, r.y);
        o.z = fmaf(beta, pv.z, r.z);
        o.w = fmaf(beta, pv.w, r.w);
        pn[v] = o;
    }
    if (blockIdx.x == 0 && threadIdx.x == 0) out[3 * (size_t)NPIX] = sums[2];
}

extern "C" void kernel_launch(void* const* d_in, const int* in_sizes, int n_in,
                              void* d_out, int out_size, void* d_ws, size_t ws_size,
                              hipStream_t stream) {
    const float* r0   = (const float*)d_in[0];
    const float* p    = (const float*)d_in[1];
    const float* phi  = (const float*)d_in[2];
    const float* filt = (const float*)d_in[3];
    float* out  = (float*)d_out;
    float* sums = (float*)d_ws;   // [0]=rr0 [1]=pAp [2]=r1_sum

    hipMemsetAsync(sums, 0, 3 * sizeof(float), stream);

    dim3 block(256);
    dim3 grid(2048);
    hipLaunchKernelGGL(k1_reduce, grid, block, 0, stream, r0, p, filt, sums);
    hipLaunchKernelGGL(k2_update, grid, block, 0, stream, r0, p, phi, filt, sums, out);
    hipLaunchKernelGGL(k3_pnew,   grid, block, 0, stream, p, sums, out);
}